// Round 1
// 310.334 us; speedup vs baseline: 1.1959x; 1.1959x over previous
//
#include <hip/hip_runtime.h>
#include <hip/hip_bf16.h>

#define PAD 68            // fp32 LDS pitch (small kernels)
#define KP  72            // bf16 LDS pitch: 144 B row -> 4-dword bank rotation, 2-way = free
#define SCALE 0.35355339059327379f

typedef __attribute__((ext_vector_type(8))) short bf16x8;
typedef __attribute__((ext_vector_type(4))) float f32x4;
#define MFMA_BF16 __builtin_amdgcn_mfma_f32_16x16x32_bf16

__device__ __forceinline__ short f2b(float f) {          // fp32 -> bf16 RNE
    unsigned u = __float_as_uint(f);
    u += 0x7fff + ((u >> 16) & 1);
    return (short)(u >> 16);
}
__device__ __forceinline__ float b2f(short h) {
    return __uint_as_float(((unsigned)(unsigned short)h) << 16);
}

__device__ __forceinline__ void fma16(float acc[16], float a, const float* b) {
    const float4* b4 = reinterpret_cast<const float4*>(b);
    float4 x0 = b4[0], x1 = b4[1], x2 = b4[2], x3 = b4[3];
    acc[0]  += a * x0.x; acc[1]  += a * x0.y; acc[2]  += a * x0.z; acc[3]  += a * x0.w;
    acc[4]  += a * x1.x; acc[5]  += a * x1.y; acc[6]  += a * x1.z; acc[7]  += a * x1.w;
    acc[8]  += a * x2.x; acc[9]  += a * x2.y; acc[10] += a * x2.z; acc[11] += a * x2.w;
    acc[12] += a * x3.x; acc[13] += a * x3.y; acc[14] += a * x3.z; acc[15] += a * x3.w;
}

// 4x4-register-tile 64x64x64 matmul step: acc = A(i0..i0+3, :) x B(:, j0..j0+3)
// A: row-major with leading dim lda (global or LDS), B: LDS row-major pitch PAD.
__device__ __forceinline__ void mm_tile(float acc[4][4],
                                        const float* __restrict__ A, int lda,
                                        const float* __restrict__ B,
                                        int i0, int j0) {
#pragma unroll
    for (int r = 0; r < 4; r++)
#pragma unroll
        for (int c = 0; c < 4; c++) acc[r][c] = 0.f;
#pragma unroll 4
    for (int k0 = 0; k0 < 64; k0 += 4) {
        float4 b0 = *reinterpret_cast<const float4*>(&B[(k0 + 0) * PAD + j0]);
        float4 b1 = *reinterpret_cast<const float4*>(&B[(k0 + 1) * PAD + j0]);
        float4 b2 = *reinterpret_cast<const float4*>(&B[(k0 + 2) * PAD + j0]);
        float4 b3 = *reinterpret_cast<const float4*>(&B[(k0 + 3) * PAD + j0]);
        float4 a0 = *reinterpret_cast<const float4*>(&A[(i0 + 0) * lda + k0]);
        float4 a1 = *reinterpret_cast<const float4*>(&A[(i0 + 1) * lda + k0]);
        float4 a2 = *reinterpret_cast<const float4*>(&A[(i0 + 2) * lda + k0]);
        float4 a3 = *reinterpret_cast<const float4*>(&A[(i0 + 3) * lda + k0]);
#define ROW_UPD(r, av) \
        acc[r][0] += av.x * b0.x + av.y * b1.x + av.z * b2.x + av.w * b3.x; \
        acc[r][1] += av.x * b0.y + av.y * b1.y + av.z * b2.y + av.w * b3.y; \
        acc[r][2] += av.x * b0.z + av.y * b1.z + av.z * b2.z + av.w * b3.z; \
        acc[r][3] += av.x * b0.w + av.y * b1.w + av.z * b2.w + av.w * b3.w;
        ROW_UPD(0, a0) ROW_UPD(1, a1) ROW_UPD(2, a2) ROW_UPD(3, a3)
#undef ROW_UPD
    }
}

// ---------- A: landmark pooling (Q,K -> Qlm,Klm, pre-scaled by SCALE/64) ----------
__global__ __launch_bounds__(256) void pool_kernel(const float* __restrict__ Q,
                                                   const float* __restrict__ K,
                                                   float* __restrict__ Qlm,
                                                   float* __restrict__ Klm) {
    __shared__ float4 red[256];
    const int blk = blockIdx.x;
    const int t = threadIdx.x;
    const int d4 = t & 15;
    const int rg = t >> 4;
    const float4* Q4 = reinterpret_cast<const float4*>(Q);
    const float4* K4 = reinterpret_cast<const float4*>(K);

    float4 sQ = {0.f, 0.f, 0.f, 0.f}, sK = {0.f, 0.f, 0.f, 0.f};
#pragma unroll
    for (int rr = 0; rr < 4; rr++) {
        int row = blk * 64 + rg * 4 + rr;
        int off4 = (row << 4) + d4;
        float4 q = Q4[off4], k = K4[off4];
        sQ.x += q.x; sQ.y += q.y; sQ.z += q.z; sQ.w += q.w;
        sK.x += k.x; sK.y += k.y; sK.z += k.z; sK.w += k.w;
    }
    const float c = SCALE * (1.0f / 64.0f);
    red[t] = sQ;
    __syncthreads();
    if (t < 16) {
        float4 s = {0.f, 0.f, 0.f, 0.f};
#pragma unroll
        for (int g = 0; g < 16; g++) {
            float4 v = red[g * 16 + t];
            s.x += v.x; s.y += v.y; s.z += v.z; s.w += v.w;
        }
        s.x *= c; s.y *= c; s.z *= c; s.w *= c;
        reinterpret_cast<float4*>(Qlm + blk * 64)[t] = s;
    }
    __syncthreads();
    red[t] = sK;
    __syncthreads();
    if (t < 16) {
        float4 s = {0.f, 0.f, 0.f, 0.f};
#pragma unroll
        for (int g = 0; g < 16; g++) {
            float4 v = red[g * 16 + t];
            s.x += v.x; s.y += v.y; s.z += v.z; s.w += v.w;
        }
        s.x *= c; s.y *= c; s.z *= c; s.w *= c;
        reinterpret_cast<float4*>(Klm + blk * 64)[t] = s;
    }
}

// ---------- B: K2 = softmax(Qlm Klm^T), global col-sum max ----------
__global__ __launch_bounds__(256) void k2_kernel(const float* __restrict__ Qlm,
                                                 const float* __restrict__ Klm,
                                                 float* __restrict__ K2g,
                                                 unsigned* __restrict__ colmax) {
    __shared__ float Ql[64 * PAD], Kl[64 * PAD], S2[64 * PAD];
    const int bh = blockIdx.x, t = threadIdx.x;
#pragma unroll
    for (int n = 0; n < 16; n++) {
        int f = t + n * 256;
        Ql[(f >> 6) * PAD + (f & 63)] = Qlm[bh * 4096 + f];
        Kl[(f >> 6) * PAD + (f & 63)] = Klm[bh * 4096 + f];
    }
    __syncthreads();
    const int i = t >> 2, j0 = (t & 3) * 16;
    float acc[16];
#pragma unroll
    for (int u = 0; u < 16; u++) acc[u] = 0.f;
    const float4* Ql4 = reinterpret_cast<const float4*>(Ql);
    const float4* Kl4 = reinterpret_cast<const float4*>(Kl);
    for (int k4 = 0; k4 < 16; k4++) {
        float4 a = Ql4[i * 17 + k4];
#pragma unroll
        for (int u = 0; u < 16; u++) {
            float4 b = Kl4[(j0 + u) * 17 + k4];
            acc[u] += a.x * b.x + a.y * b.y + a.z * b.z + a.w * b.w;
        }
    }
#pragma unroll
    for (int u = 0; u < 16; u++) S2[i * PAD + j0 + u] = acc[u];
    __syncthreads();
    if (t < 64) {
        float m = -1e30f;
        for (int j = 0; j < 64; j++) m = fmaxf(m, S2[t * PAD + j]);
        float sum = 0.f;
        for (int j = 0; j < 64; j++) {
            float e = __expf(S2[t * PAD + j] - m);
            S2[t * PAD + j] = e; sum += e;
        }
        float inv = 1.0f / sum;
        for (int j = 0; j < 64; j++) S2[t * PAD + j] *= inv;
    }
    __syncthreads();
#pragma unroll
    for (int n = 0; n < 16; n++) {
        int f = t + n * 256;
        K2g[bh * 4096 + f] = S2[(f >> 6) * PAD + (f & 63)];
    }
    if (t < 64) {
        float c = 0.f;
        for (int ii = 0; ii < 64; ii++) c += S2[ii * PAD + t];
        atomicMax(colmax, __float_as_uint(c));
    }
}

// ---------- C+D fused: blocks 0..63 do Newton-Schulz inverse (latency-bound,
//            1 block/CU), blocks 64..1087 do k3v MFMA (memory/MFMA-bound).
//            Independent work: inverse hides completely under k3v's bandwidth. ----------
__global__ __launch_bounds__(256) void fused_inv_k3v(const float* __restrict__ Qlm,
                                                     const float* __restrict__ K,
                                                     const float* __restrict__ V,
                                                     float* __restrict__ W2acc,
                                                     float* __restrict__ rowsum3,
                                                     const float* __restrict__ K2g,
                                                     const unsigned* __restrict__ colmax,
                                                     float* __restrict__ K2invg) {
    // union: inverse needs 3 x 64*PAD fp32 (52224 B); k3v needs 4 x 64*KP bf16 (36864 B)
    __shared__ __align__(16) char smem[64 * PAD * 4 * 3];
    const int t = threadIdx.x;

    if (blockIdx.x < 64) {
        // ================= Newton-Schulz inverse (6 iters, 4x4 reg tiles) ========
        float* Vb = reinterpret_cast<float*>(smem);
        float* Ab = Vb + 64 * PAD;
        float* Tb = Ab + 64 * PAD;
        const int bh = blockIdx.x;
        const float sc = 1.0f / __uint_as_float(*colmax);
        const float* Kg = K2g + bh * 4096;
#pragma unroll
        for (int n = 0; n < 16; n++) {
            int f = t + n * 256;
            Vb[(f >> 6) * PAD + (f & 63)] = sc * Kg[(f & 63) * 64 + (f >> 6)];
        }
        __syncthreads();
        const int i0 = (t >> 4) * 4, j0 = (t & 15) * 4;
        float acc[4][4], vacc[4][4];
        for (int iter = 0; iter < 6; iter++) {
            // mm1: Ab = Kg . Vb   (Kg stays in global: 16 KB, L1-resident)
            mm_tile(acc, Kg, 64, Vb, i0, j0);
#pragma unroll
            for (int r = 0; r < 4; r++)
                *reinterpret_cast<float4*>(&Ab[(i0 + r) * PAD + j0]) =
                    make_float4(acc[r][0], acc[r][1], acc[r][2], acc[r][3]);
            __syncthreads();
            // mm2: acc = Vb . Ab ; vacc = 13 Vb - 15 acc ; Tb = acc
            mm_tile(acc, Vb, PAD, Ab, i0, j0);
#pragma unroll
            for (int r = 0; r < 4; r++) {
                float4 v = *reinterpret_cast<const float4*>(&Vb[(i0 + r) * PAD + j0]);
                vacc[r][0] = 13.f * v.x - 15.f * acc[r][0];
                vacc[r][1] = 13.f * v.y - 15.f * acc[r][1];
                vacc[r][2] = 13.f * v.z - 15.f * acc[r][2];
                vacc[r][3] = 13.f * v.w - 15.f * acc[r][3];
                *reinterpret_cast<float4*>(&Tb[(i0 + r) * PAD + j0]) =
                    make_float4(acc[r][0], acc[r][1], acc[r][2], acc[r][3]);
            }
            __syncthreads();
            // mm3: acc = Tb . Ab ; vacc += 7 acc ; Vb = acc
            mm_tile(acc, Tb, PAD, Ab, i0, j0);
#pragma unroll
            for (int r = 0; r < 4; r++) {
                vacc[r][0] += 7.f * acc[r][0];
                vacc[r][1] += 7.f * acc[r][1];
                vacc[r][2] += 7.f * acc[r][2];
                vacc[r][3] += 7.f * acc[r][3];
                *reinterpret_cast<float4*>(&Vb[(i0 + r) * PAD + j0]) =
                    make_float4(acc[r][0], acc[r][1], acc[r][2], acc[r][3]);
            }
            __syncthreads();
            // mm4: acc = Vb . Ab ; vacc -= acc
            mm_tile(acc, Vb, PAD, Ab, i0, j0);
#pragma unroll
            for (int r = 0; r < 4; r++) {
                vacc[r][0] -= acc[r][0]; vacc[r][1] -= acc[r][1];
                vacc[r][2] -= acc[r][2]; vacc[r][3] -= acc[r][3];
            }
            __syncthreads();
#pragma unroll
            for (int r = 0; r < 4; r++)
                *reinterpret_cast<float4*>(&Vb[(i0 + r) * PAD + j0]) =
                    make_float4(0.25f * vacc[r][0], 0.25f * vacc[r][1],
                                0.25f * vacc[r][2], 0.25f * vacc[r][3]);
            __syncthreads();
        }
#pragma unroll
        for (int n = 0; n < 16; n++) {
            int f = t + n * 256;
            K2invg[bh * 4096 + f] = Vb[(f >> 6) * PAD + (f & 63)];
        }
        return;
    }

    // ================= k3v: W2acc += exp(Qlm (SCALE*K)^T) @ V ; rowsum3 += exp-sums ====
    short* Qs = reinterpret_cast<short*>(smem);            // A (mm1): [landmark][dim]
    short* Kt = Qs + 64 * KP;                              // B (mm1): [key][dim]
    short* Vt = Kt + 64 * KP;                              // B (mm2): [dim][key]
    short* Eb = Vt + 64 * KP;                              // A (mm2): [landmark][key]
    const int idx = blockIdx.x - 64;
    const int chunk = idx & 15, bh = idx >> 4;
    const int w = t >> 6, lane = t & 63, quad = lane >> 4, l15 = lane & 15;
    const float4* Qlm4 = reinterpret_cast<const float4*>(Qlm);
    const float4* K4 = reinterpret_cast<const float4*>(K);
    const float4* V4 = reinterpret_cast<const float4*>(V);

    // stage Qlm (already SCALE/64-scaled by pool)
#pragma unroll
    for (int n = 0; n < 4; n++) {
        int f4 = t + n * 256;
        int r = f4 >> 4, dg = f4 & 15;
        float4 q = Qlm4[bh * 1024 + f4];
        ushort4 uq = { (unsigned short)f2b(q.x), (unsigned short)f2b(q.y),
                       (unsigned short)f2b(q.z), (unsigned short)f2b(q.w) };
        *reinterpret_cast<ushort4*>(&Qs[r * KP + dg * 4]) = uq;
    }

    f32x4 oacc[4];
    float rsum[4];
#pragma unroll
    for (int nt = 0; nt < 4; nt++) { oacc[nt] = (f32x4){0.f, 0.f, 0.f, 0.f}; rsum[nt] = 0.f; }

    for (int tile = 0; tile < 4; tile++) {
        const int sb = chunk * 256 + tile * 64;
        __syncthreads();   // protect Kt/Vt (prev matmuls) and Eb (prev matmul2)
        // stage K (scaled, row-major) and V (transposed)
#pragma unroll
        for (int n = 0; n < 4; n++) {
            int f4 = t + n * 256;
            int key = f4 >> 4, dg = f4 & 15;
            int g4 = (bh * 4096 + sb + key) * 16 + dg;
            float4 kk = K4[g4];
            ushort4 uk = { (unsigned short)f2b(SCALE * kk.x), (unsigned short)f2b(SCALE * kk.y),
                           (unsigned short)f2b(SCALE * kk.z), (unsigned short)f2b(SCALE * kk.w) };
            *reinterpret_cast<ushort4*>(&Kt[key * KP + dg * 4]) = uk;
            float4 vv = V4[g4];
            Vt[(dg * 4 + 0) * KP + key] = f2b(vv.x);
            Vt[(dg * 4 + 1) * KP + key] = f2b(vv.y);
            Vt[(dg * 4 + 2) * KP + key] = f2b(vv.z);
            Vt[(dg * 4 + 3) * KP + key] = f2b(vv.w);
        }
        __syncthreads();
        // matmul1: S[m=16w.., n=key] = Qlm . Kt^T
        bf16x8 a0 = *reinterpret_cast<const bf16x8*>(&Qs[(w * 16 + l15) * KP + quad * 8]);
        bf16x8 a1 = *reinterpret_cast<const bf16x8*>(&Qs[(w * 16 + l15) * KP + quad * 8 + 32]);
#pragma unroll
        for (int nt = 0; nt < 4; nt++) {
            bf16x8 b0 = *reinterpret_cast<const bf16x8*>(&Kt[(nt * 16 + l15) * KP + quad * 8]);
            bf16x8 b1 = *reinterpret_cast<const bf16x8*>(&Kt[(nt * 16 + l15) * KP + quad * 8 + 32]);
            f32x4 c = {0.f, 0.f, 0.f, 0.f};
            c = MFMA_BF16(a0, b0, c, 0, 0, 0);
            c = MFMA_BF16(a1, b1, c, 0, 0, 0);
#pragma unroll
            for (int reg = 0; reg < 4; reg++) {
                float e = __expf(c[reg]);
                rsum[reg] += e;
                Eb[(w * 16 + quad * 4 + reg) * KP + nt * 16 + l15] = f2b(e);
            }
        }
        // matmul2: oacc += E . Vt^T   (wave reads only its own E rows -> no barrier)
        bf16x8 e0 = *reinterpret_cast<const bf16x8*>(&Eb[(w * 16 + l15) * KP + quad * 8]);
        bf16x8 e1 = *reinterpret_cast<const bf16x8*>(&Eb[(w * 16 + l15) * KP + quad * 8 + 32]);
#pragma unroll
        for (int nt = 0; nt < 4; nt++) {
            bf16x8 b0 = *reinterpret_cast<const bf16x8*>(&Vt[(nt * 16 + l15) * KP + quad * 8]);
            bf16x8 b1 = *reinterpret_cast<const bf16x8*>(&Vt[(nt * 16 + l15) * KP + quad * 8 + 32]);
            oacc[nt] = MFMA_BF16(e0, b0, oacc[nt], 0, 0, 0);
            oacc[nt] = MFMA_BF16(e1, b1, oacc[nt], 0, 0, 0);
        }
    }
    // reduce rowsums over the 16 lanes of each quad
#pragma unroll
    for (int reg = 0; reg < 4; reg++) {
        float s = rsum[reg];
        s += __shfl_xor(s, 1); s += __shfl_xor(s, 2);
        s += __shfl_xor(s, 4); s += __shfl_xor(s, 8);
        rsum[reg] = s;
    }
    const int row0 = w * 16 + quad * 4;
    if (l15 == 0) {
#pragma unroll
        for (int reg = 0; reg < 4; reg++)
            atomicAdd(&rowsum3[bh * 64 + row0 + reg], rsum[reg]);
    }
#pragma unroll
    for (int nt = 0; nt < 4; nt++)
#pragma unroll
        for (int reg = 0; reg < 4; reg++)
            atomicAdd(&W2acc[(bh * 64 + row0 + reg) * 64 + nt * 16 + l15], oacc[nt][reg]);
}

// ---------- E: W = inv(K2) @ (W2acc / rowsum3) ----------
__global__ __launch_bounds__(256) void wmid_kernel(const float* __restrict__ K2invg,
                                                   const float* __restrict__ W2acc,
                                                   const float* __restrict__ rowsum3,
                                                   float* __restrict__ Wg) {
    __shared__ float I1[64 * PAD], W2[64 * PAD];
    const int bh = blockIdx.x, t = threadIdx.x;
#pragma unroll
    for (int n = 0; n < 16; n++) {
        int f = t + n * 256;
        int r = f >> 6;
        I1[r * PAD + (f & 63)] = K2invg[bh * 4096 + f];
        W2[r * PAD + (f & 63)] = W2acc[bh * 4096 + f] / rowsum3[bh * 64 + r];
    }
    __syncthreads();
    const int i = t >> 2, j0 = (t & 3) * 16;
    float acc[16];
#pragma unroll
    for (int u = 0; u < 16; u++) acc[u] = 0.f;
    for (int k = 0; k < 64; k++) fma16(acc, I1[i * PAD + k], W2 + k * PAD + j0);
#pragma unroll
    for (int u = 0; u < 16; u++) Wg[bh * 4096 + i * 64 + j0 + u] = acc[u];
}

// ---------- F (MFMA): X = softmax((SCALE*Q) Klm^T) @ W ----------
__global__ __launch_bounds__(256) void final_mfma(const float* __restrict__ Q,
                                                  const float* __restrict__ Klm,
                                                  const float* __restrict__ Wg,
                                                  float* __restrict__ out) {
    __shared__ short Qs[64 * KP];   // A (mm1): [seqrow][dim]
    __shared__ short Kl[64 * KP];   // B (mm1): [landmark][dim]
    __shared__ short Eb[64 * KP];   // A (mm2): [seqrow][landmark]
    __shared__ short Wh[64 * KP];   // B (mm2) hi: [dim][landmark]
    __shared__ short Wl[64 * KP];   // B (mm2) lo
    const int sc = blockIdx.x, bh = blockIdx.y, t = threadIdx.x;
    const int w = t >> 6, lane = t & 63, quad = lane >> 4, l15 = lane & 15;
    const int s0 = sc * 64;
    const float4* Q4 = reinterpret_cast<const float4*>(Q);
    const float4* Klm4 = reinterpret_cast<const float4*>(Klm);
    const float4* W4 = reinterpret_cast<const float4*>(Wg);

#pragma unroll
    for (int n = 0; n < 4; n++) {
        int f4 = t + n * 256;
        int r = f4 >> 4, dg = f4 & 15;
        // Klm row-major (already scaled)
        float4 kl = Klm4[bh * 1024 + f4];
        ushort4 uk = { (unsigned short)f2b(kl.x), (unsigned short)f2b(kl.y),
                       (unsigned short)f2b(kl.z), (unsigned short)f2b(kl.w) };
        *reinterpret_cast<ushort4*>(&Kl[r * KP + dg * 4]) = uk;
        // Q tile, scaled
        float4 q = Q4[(bh * 4096 + s0 + r) * 16 + dg];
        ushort4 uq = { (unsigned short)f2b(SCALE * q.x), (unsigned short)f2b(SCALE * q.y),
                       (unsigned short)f2b(SCALE * q.z), (unsigned short)f2b(SCALE * q.w) };
        *reinterpret_cast<ushort4*>(&Qs[r * KP + dg * 4]) = uq;
        // W split hi/lo, transposed: Wh[dim][landmark]
        float4 ww = W4[bh * 1024 + f4];     // W[r=landmark][dg*4..]
        float wv[4] = {ww.x, ww.y, ww.z, ww.w};
#pragma unroll
        for (int i = 0; i < 4; i++) {
            short hi = f2b(wv[i]);
            Wh[(dg * 4 + i) * KP + r] = hi;
            Wl[(dg * 4 + i) * KP + r] = f2b(wv[i] - b2f(hi));
        }
    }
    __syncthreads();
    // mm1: S = Qs . Kl^T ; exp ; rowsum ; Eb
    bf16x8 a0 = *reinterpret_cast<const bf16x8*>(&Qs[(w * 16 + l15) * KP + quad * 8]);
    bf16x8 a1 = *reinterpret_cast<const bf16x8*>(&Qs[(w * 16 + l15) * KP + quad * 8 + 32]);
    float rsum[4] = {0.f, 0.f, 0.f, 0.f};
#pragma unroll
    for (int nt = 0; nt < 4; nt++) {
        bf16x8 b0 = *reinterpret_cast<const bf16x8*>(&Kl[(nt * 16 + l15) * KP + quad * 8]);
        bf16x8 b1 = *reinterpret_cast<const bf16x8*>(&Kl[(nt * 16 + l15) * KP + quad * 8 + 32]);
        f32x4 c = {0.f, 0.f, 0.f, 0.f};
        c = MFMA_BF16(a0, b0, c, 0, 0, 0);
        c = MFMA_BF16(a1, b1, c, 0, 0, 0);
#pragma unroll
        for (int reg = 0; reg < 4; reg++) {
            float e = __expf(c[reg]);
            rsum[reg] += e;
            Eb[(w * 16 + quad * 4 + reg) * KP + nt * 16 + l15] = f2b(e);
        }
    }
#pragma unroll
    for (int reg = 0; reg < 4; reg++) {
        float s = rsum[reg];
        s += __shfl_xor(s, 1); s += __shfl_xor(s, 2);
        s += __shfl_xor(s, 4); s += __shfl_xor(s, 8);
        rsum[reg] = 1.0f / s;
    }
    // mm2: X = Eb . (Wh + Wl)   (wave reads only its own Eb rows -> no barrier needed)
    bf16x8 e0 = *reinterpret_cast<const bf16x8*>(&Eb[(w * 16 + l15) * KP + quad * 8]);
    bf16x8 e1 = *reinterpret_cast<const bf16x8*>(&Eb[(w * 16 + l15) * KP + quad * 8 + 32]);
    const int row0 = w * 16 + quad * 4;
#pragma unroll
    for (int nt = 0; nt < 4; nt++) {
        bf16x8 bh0 = *reinterpret_cast<const bf16x8*>(&Wh[(nt * 16 + l15) * KP + quad * 8]);
        bf16x8 bh1 = *reinterpret_cast<const bf16x8*>(&Wh[(nt * 16 + l15) * KP + quad * 8 + 32]);
        bf16x8 bl0 = *reinterpret_cast<const bf16x8*>(&Wl[(nt * 16 + l15) * KP + quad * 8]);
        bf16x8 bl1 = *reinterpret_cast<const bf16x8*>(&Wl[(nt * 16 + l15) * KP + quad * 8 + 32]);
        f32x4 c = {0.f, 0.f, 0.f, 0.f};
        c = MFMA_BF16(e0, bh0, c, 0, 0, 0);
        c = MFMA_BF16(e1, bh1, c, 0, 0, 0);
        c = MFMA_BF16(e0, bl0, c, 0, 0, 0);
        c = MFMA_BF16(e1, bl1, c, 0, 0, 0);
#pragma unroll
        for (int reg = 0; reg < 4; reg++)
            out[((size_t)bh * 4096 + s0 + row0 + reg) * 64 + nt * 16 + l15] = c[reg] * rsum[reg];
    }
}

extern "C" void kernel_launch(void* const* d_in, const int* in_sizes, int n_in,
                              void* d_out, int out_size, void* d_ws, size_t ws_size,
                              hipStream_t stream) {
    const float* Q = (const float*)d_in[0];
    const float* K = (const float*)d_in[1];
    const float* V = (const float*)d_in[2];
    float* out = (float*)d_out;
    float* ws = (float*)d_ws;

    float* Qlm    = ws;
    float* Klm    = ws + 262144;
    float* K2     = ws + 524288;
    float* K2inv  = ws + 786432;
    float* Wg     = ws + 1048576;
    float* W2acc  = ws + 1310720;       // zeroed
    float* rowsum3 = ws + 1572864;      // zeroed
    unsigned* colmax = (unsigned*)(ws + 1576960);  // zeroed

    hipMemsetAsync(W2acc, 0, (262144 + 4096 + 1) * sizeof(float), stream);

    pool_kernel<<<4096, 256, 0, stream>>>(Q, K, Qlm, Klm);
    k2_kernel<<<64, 256, 0, stream>>>(Qlm, Klm, K2, colmax);
    // blocks 0..63: Newton-Schulz inverse (needs K2/colmax); blocks 64..1087: k3v
    fused_inv_k3v<<<1088, 256, 0, stream>>>(Qlm, K, V, W2acc, rowsum3, K2, colmax, K2inv);
    wmid_kernel<<<64, 256, 0, stream>>>(K2inv, W2acc, rowsum3, Wg);
    final_mfma<<<dim3(64, 64), 256, 0, stream>>>(Q, Klm, Wg, out);
}